// Round 1
// baseline (495.229 us; speedup 1.0000x reference)
//
#include <hip/hip_runtime.h>
#include <hip/hip_bf16.h>

#define BN 24
#define BATCH 4
#define NCAM 6
#define CF 80
#define C2 64
#define DD 112
#define HH 16
#define WW 44
#define KTOT 264
#define XY 16384

// ---------------- K1: conv3x3(80->64) + ReLU ----------------
// block = (bn, h): 24*16 = 384 blocks, 256 threads.
// LDS: input rows h-1,h,h+1 for all 80 channels. Thread: co = t>>2, w-strip of 11.
__global__ __launch_bounds__(256) void k1_conv1(const float* __restrict__ feat,
                                                const float* __restrict__ w1,
                                                const float* __restrict__ b1,
                                                float* __restrict__ hbuf) {
    int bn = blockIdx.x >> 4;
    int h  = blockIdx.x & 15;
    __shared__ float fs[CF][3][WW];
    int t = threadIdx.x;
    for (int i = t; i < CF * 3 * WW; i += 256) {
        int ci = i / (3 * WW);
        int r  = i % (3 * WW);
        int ky = r / WW;
        int x  = r % WW;
        int y  = h + ky - 1;
        fs[ci][ky][x] = (y >= 0 && y < HH) ? feat[((bn * CF + ci) * HH + y) * WW + x] : 0.f;
    }
    __syncthreads();
    int co = t >> 2;        // 0..63
    int wq = t & 3;         // 0..3
    int w0 = wq * 11;       // strip start
    float acc[11];
    float bias = b1[co];
#pragma unroll
    for (int j = 0; j < 11; ++j) acc[j] = bias;
    for (int ci = 0; ci < CF; ++ci) {
#pragma unroll
        for (int ky = 0; ky < 3; ++ky) {
            float r[13];
#pragma unroll
            for (int i = 0; i < 13; ++i) {
                int x = w0 - 1 + i;
                r[i] = (x >= 0 && x < WW) ? fs[ci][ky][x] : 0.f;
            }
            const float* wp = &w1[((co * CF + ci) * 3 + ky) * 3];
#pragma unroll
            for (int kx = 0; kx < 3; ++kx) {
                float wv = wp[kx];
#pragma unroll
                for (int j = 0; j < 11; ++j) acc[j] += wv * r[j + kx];
            }
        }
    }
#pragma unroll
    for (int j = 0; j < 11; ++j) {
        float v = acc[j] > 0.f ? acc[j] : 0.f;
        hbuf[((bn * C2 + co) * HH + h) * WW + w0 + j] = v;
    }
}

// ---------------- K2: conv3x3(64->1) + softmax over H -> vert_w ----------------
// block = (bn, w-quarter): 24*4 = 96 blocks. 176 pixels per block.
__global__ __launch_bounds__(256) void k2_vertw(const float* __restrict__ hbuf,
                                                const float* __restrict__ w2,
                                                const float* __restrict__ b2,
                                                float* __restrict__ vw) {
    int bn = blockIdx.x >> 2;
    int wq = blockIdx.x & 3;
    int wbase = wq * 11;
    __shared__ float slog[HH][11];
    int t = threadIdx.x;
    if (t < HH * 11) {
        int h = t / 11;
        int w = wbase + t % 11;
        float acc = b2[0];
        for (int ci = 0; ci < C2; ++ci) {
            const float* hb = &hbuf[(bn * C2 + ci) * HH * WW];
            const float* wp = &w2[ci * 9];
#pragma unroll
            for (int ky = 0; ky < 3; ++ky) {
                int y = h + ky - 1;
                if (y < 0 || y >= HH) continue;
#pragma unroll
                for (int kx = 0; kx < 3; ++kx) {
                    int x = w + kx - 1;
                    if (x < 0 || x >= WW) continue;
                    acc += wp[ky * 3 + kx] * hb[y * WW + x];
                }
            }
        }
        slog[h][t % 11] = acc;
    }
    __syncthreads();
    if (t < 11) {
        int w = wbase + t;
        float m = -1e30f;
        for (int h = 0; h < HH; ++h) m = fmaxf(m, slog[h][t]);
        float s = 0.f;
        for (int h = 0; h < HH; ++h) s += expf(slog[h][t] - m);
        float inv = 1.f / s;
        for (int h = 0; h < HH; ++h)
            vw[bn * HH * WW + h * WW + w] = expf(slog[h][t] - m) * inv;
    }
}

// ---------------- K3: softmax over D  *  vert_w, summed over H -> dp[b][k][d] ----------------
// block per (bn, w): 1056 blocks. 16 groups of 16 lanes; group g handles h=g.
__global__ __launch_bounds__(256) void k3_depth(const float* __restrict__ dl,
                                                const float* __restrict__ vw,
                                                float* __restrict__ dp) {
    int bx = blockIdx.x;
    int bn = bx / WW;
    int w  = bx % WW;
    __shared__ float sl[HH][DD];
    int t = threadIdx.x;
    for (int e = t; e < HH * DD; e += 256) {
        int d = e % DD, h = e / DD;
        sl[h][d] = dl[((bn * DD + d) * HH + h) * WW + w];
    }
    __syncthreads();
    int g = t >> 4;   // h
    int l = t & 15;
    float v[7];
#pragma unroll
    for (int j = 0; j < 7; ++j) v[j] = sl[g][l + 16 * j];
    float m = v[0];
#pragma unroll
    for (int j = 1; j < 7; ++j) m = fmaxf(m, v[j]);
#pragma unroll
    for (int mk = 1; mk < 16; mk <<= 1) m = fmaxf(m, __shfl_xor(m, mk, 64));
    float s = 0.f;
#pragma unroll
    for (int j = 0; j < 7; ++j) { v[j] = expf(v[j] - m); s += v[j]; }
#pragma unroll
    for (int mk = 1; mk < 16; mk <<= 1) s += __shfl_xor(s, mk, 64);
    float wv = vw[bn * HH * WW + g * WW + w] / s;
#pragma unroll
    for (int j = 0; j < 7; ++j) sl[g][l + 16 * j] = v[j] * wv;
    __syncthreads();
    if (t < DD) {
        float acc = 0.f;
#pragma unroll
        for (int h = 0; h < HH; ++h) acc += sl[h][t];
        int b = bn / NCAM, n = bn % NCAM;
        dp[(size_t)(b * KTOT + n * WW + w) * DD + t] = acc;
    }
}

// ---------------- K4: feat max over H -> fp[b][k][c] ----------------
__global__ __launch_bounds__(256) void k4_featmax(const float* __restrict__ feat,
                                                  float* __restrict__ fp) {
    int tid = blockIdx.x * 256 + threadIdx.x;
    if (tid >= BN * CF * WW) return;
    int bn = tid / (CF * WW);
    int r  = tid % (CF * WW);
    int c = r / WW, w = r % WW;
    float m = -1e30f;
    for (int h = 0; h < HH; ++h)
        m = fmaxf(m, feat[((bn * CF + c) * HH + h) * WW + w]);
    int b = bn / NCAM, n = bn % NCAM;
    fp[(size_t)(b * KTOT + n * WW + w) * CF + c] = m;
}

// ---------------- K5: fused MatrixVT projection ----------------
// bev[b,v,c] = sum_k (sum_d dp[k,d]*circle[d,v]) * ray[k,v] * fp[k,c]
// block = (b, 64-wide v tile): 4*256 = 1024 blocks, 256 threads.
__global__ __launch_bounds__(256) void k5_bev(const float* __restrict__ dp,
                                              const float* __restrict__ fp,
                                              const float* __restrict__ circle,
                                              const float* __restrict__ ray,
                                              float* __restrict__ out) {
    int b  = blockIdx.x >> 8;
    int vt = blockIdx.x & 255;
    int v0 = vt * 64;
    __shared__ __align__(16) float cs[DD][64];   // 28 KB circle tile (resident)
    __shared__ __align__(16) float dps[32][DD];  // 14 KB k-chunk of dp
    __shared__ __align__(16) float fps[32][CF];  // 10 KB k-chunk of fp
    __shared__ __align__(16) float prj[32][64];  //  8 KB proj chunk
    int t = threadIdx.x;

    const float* cb = circle + (size_t)b * DD * XY + v0;
    for (int e = t; e < DD * 64; e += 256) {
        int d = e >> 6, vv = e & 63;
        cs[d][vv] = cb[(size_t)d * XY + vv];
    }

    // accumulate mapping: 4 v x 5 c per thread
    int vv0 = (t & 15) * 4;
    int c0  = (t >> 4) * 5;
    float acc[4][5];
#pragma unroll
    for (int i = 0; i < 4; ++i)
#pragma unroll
        for (int j = 0; j < 5; ++j) acc[i][j] = 0.f;

    // proj mapping: 2 k x 4 v per thread
    int kk0 = (t >> 4) * 2;
    int vp  = (t & 15) * 4;
    __syncthreads();

    for (int kc = 0; kc < 9; ++kc) {
        int k0 = kc * 32;
        // stage dp / fp k-chunks (zero-pad k>=264)
        for (int e = t; e < 32 * DD; e += 256) {
            int kk = e / DD, d = e % DD;
            int k = k0 + kk;
            dps[kk][d] = (k < KTOT) ? dp[((size_t)b * KTOT + k) * DD + d] : 0.f;
        }
        for (int e = t; e < 32 * CF; e += 256) {
            int kk = e / CF, c = e % CF;
            int k = k0 + kk;
            fps[kk][c] = (k < KTOT) ? fp[((size_t)b * KTOT + k) * CF + c] : 0.f;
        }
        __syncthreads();
        // proj chunk: prj[kk][vv] = (sum_d dps[kk][d]*cs[d][vv]) * ray[k][v0+vv]
        float s0[4] = {0.f, 0.f, 0.f, 0.f};
        float s1[4] = {0.f, 0.f, 0.f, 0.f};
        for (int d = 0; d < DD; ++d) {
            float a0 = dps[kk0][d];
            float a1 = dps[kk0 + 1][d];
            const float4 cv = *(const float4*)&cs[d][vp];
            s0[0] += a0 * cv.x; s0[1] += a0 * cv.y; s0[2] += a0 * cv.z; s0[3] += a0 * cv.w;
            s1[0] += a1 * cv.x; s1[1] += a1 * cv.y; s1[2] += a1 * cv.z; s1[3] += a1 * cv.w;
        }
        {
            int k = k0 + kk0;
            if (k < KTOT) {
                const float4 rv = *(const float4*)&ray[((size_t)b * KTOT + k) * XY + v0 + vp];
                float4 pw;
                pw.x = s0[0] * rv.x; pw.y = s0[1] * rv.y; pw.z = s0[2] * rv.z; pw.w = s0[3] * rv.w;
                *(float4*)&prj[kk0][vp] = pw;
            } else {
                *(float4*)&prj[kk0][vp] = float4{0.f, 0.f, 0.f, 0.f};
            }
            k = k0 + kk0 + 1;
            if (k < KTOT) {
                const float4 rv = *(const float4*)&ray[((size_t)b * KTOT + k) * XY + v0 + vp];
                float4 pw;
                pw.x = s1[0] * rv.x; pw.y = s1[1] * rv.y; pw.z = s1[2] * rv.z; pw.w = s1[3] * rv.w;
                *(float4*)&prj[kk0 + 1][vp] = pw;
            } else {
                *(float4*)&prj[kk0 + 1][vp] = float4{0.f, 0.f, 0.f, 0.f};
            }
        }
        __syncthreads();
        // accumulate bev tile
        for (int kk = 0; kk < 32; ++kk) {
            const float4 pv = *(const float4*)&prj[kk][vv0];
            float f[5];
#pragma unroll
            for (int j = 0; j < 5; ++j) f[j] = fps[kk][c0 + j];
#pragma unroll
            for (int j = 0; j < 5; ++j) {
                acc[0][j] += pv.x * f[j];
                acc[1][j] += pv.y * f[j];
                acc[2][j] += pv.z * f[j];
                acc[3][j] += pv.w * f[j];
            }
        }
        __syncthreads();
    }
    // epilogue: out[b][c][v]
    float* ob = out + (size_t)b * CF * XY + v0 + vv0;
#pragma unroll
    for (int j = 0; j < 5; ++j) {
        float4 o;
        o.x = acc[0][j]; o.y = acc[1][j]; o.z = acc[2][j]; o.w = acc[3][j];
        *(float4*)&ob[(size_t)(c0 + j) * XY] = o;
    }
}

extern "C" void kernel_launch(void* const* d_in, const int* in_sizes, int n_in,
                              void* d_out, int out_size, void* d_ws, size_t ws_size,
                              hipStream_t stream) {
    const float* feat   = (const float*)d_in[0];
    const float* dl     = (const float*)d_in[1];
    const float* circle = (const float*)d_in[2];
    const float* ray    = (const float*)d_in[3];
    const float* w1     = (const float*)d_in[4];
    const float* b1     = (const float*)d_in[5];
    const float* w2     = (const float*)d_in[6];
    const float* b2     = (const float*)d_in[7];
    float* out = (float*)d_out;

    float* ws   = (float*)d_ws;
    float* hbuf = ws;                    // 24*64*16*44 = 1,081,344 floats
    float* vw   = hbuf + 1081344;        // 24*16*44    =    16,896
    float* dp   = vw + 16896;            // 4*264*112   =   118,272
    float* fp   = dp + 118272;           // 4*264*80    =    84,480  (total ~5.2 MB)

    hipLaunchKernelGGL(k1_conv1, dim3(384), dim3(256), 0, stream, feat, w1, b1, hbuf);
    hipLaunchKernelGGL(k2_vertw, dim3(96), dim3(256), 0, stream, hbuf, w2, b2, vw);
    hipLaunchKernelGGL(k3_depth, dim3(BN * WW), dim3(256), 0, stream, dl, vw, dp);
    hipLaunchKernelGGL(k4_featmax, dim3((BN * CF * WW + 255) / 256), dim3(256), 0, stream, feat, fp);
    hipLaunchKernelGGL(k5_bev, dim3(1024), dim3(256), 0, stream, dp, fp, circle, ray, out);
}

// Round 2
// 323.391 us; speedup vs baseline: 1.5314x; 1.5314x over previous
//
#include <hip/hip_runtime.h>
#include <hip/hip_bf16.h>

#define BN 24
#define BATCH 4
#define NCAM 6
#define CF 80
#define C2 64
#define DD 112
#define HH 16
#define WW 44
#define KTOT 264
#define KPAD 288
#define DPAD 128
#define XY 16384
#define VT 64
#define KC 96

typedef __bf16 bf16x8 __attribute__((ext_vector_type(8)));
typedef float f32x4 __attribute__((ext_vector_type(4)));

// ---------------- K1: conv3x3(80->64) + ReLU (padded LDS, branch-free inner) ----------------
__global__ __launch_bounds__(256) void k1_conv1(const float* __restrict__ feat,
                                                const float* __restrict__ w1,
                                                const float* __restrict__ b1,
                                                float* __restrict__ hbuf) {
    int bn = blockIdx.x >> 4;
    int h  = blockIdx.x & 15;
    __shared__ float fs[CF][3][48];   // x index = w+1; zeros at 0, 45..47
    int t = threadIdx.x;
    for (int e = t; e < CF * 3 * 48; e += 256) {
        int ci = e / 144;
        int r  = e % 144;
        int ky = r / 48;
        int x  = r % 48;
        int y  = h + ky - 1;
        int xs = x - 1;
        float v = 0.f;
        if (y >= 0 && y < HH && xs >= 0 && xs < WW)
            v = feat[((bn * CF + ci) * HH + y) * WW + xs];
        fs[ci][ky][x] = v;
    }
    __syncthreads();
    int co = t >> 2;        // 0..63
    int wq = t & 3;         // 0..3
    int w0 = wq * 11;
    float acc[11];
    float bias = b1[co];
#pragma unroll
    for (int j = 0; j < 11; ++j) acc[j] = bias;
    for (int ci = 0; ci < CF; ++ci) {
#pragma unroll
        for (int ky = 0; ky < 3; ++ky) {
            float r[13];
#pragma unroll
            for (int i = 0; i < 13; ++i) r[i] = fs[ci][ky][w0 + i];
            const float* wp = &w1[((co * CF + ci) * 3 + ky) * 3];
#pragma unroll
            for (int kx = 0; kx < 3; ++kx) {
                float wv = wp[kx];
#pragma unroll
                for (int j = 0; j < 11; ++j) acc[j] += wv * r[j + kx];
            }
        }
    }
#pragma unroll
    for (int j = 0; j < 11; ++j) {
        float v = acc[j] > 0.f ? acc[j] : 0.f;
        hbuf[((bn * C2 + co) * HH + h) * WW + w0 + j] = v;
    }
}

// ---------------- K2: conv3x3(64->1) + softmax over H -> vert_w ----------------
__global__ __launch_bounds__(256) void k2_vertw(const float* __restrict__ hbuf,
                                                const float* __restrict__ w2,
                                                const float* __restrict__ b2,
                                                float* __restrict__ vw) {
    int bn = blockIdx.x >> 2;
    int wq = blockIdx.x & 3;
    int wbase = wq * 11;
    __shared__ float slog[HH][11];
    int t = threadIdx.x;
    if (t < HH * 11) {
        int h = t / 11;
        int w = wbase + t % 11;
        float acc = b2[0];
        for (int ci = 0; ci < C2; ++ci) {
            const float* hb = &hbuf[(bn * C2 + ci) * HH * WW];
            const float* wp = &w2[ci * 9];
#pragma unroll
            for (int ky = 0; ky < 3; ++ky) {
                int y = h + ky - 1;
                if (y < 0 || y >= HH) continue;
#pragma unroll
                for (int kx = 0; kx < 3; ++kx) {
                    int x = w + kx - 1;
                    if (x < 0 || x >= WW) continue;
                    acc += wp[ky * 3 + kx] * hb[y * WW + x];
                }
            }
        }
        slog[h][t % 11] = acc;
    }
    __syncthreads();
    if (t < 11) {
        int w = wbase + t;
        float m = -1e30f;
        for (int h = 0; h < HH; ++h) m = fmaxf(m, slog[h][t]);
        float s = 0.f;
        for (int h = 0; h < HH; ++h) s += expf(slog[h][t] - m);
        float inv = 1.f / s;
        for (int h = 0; h < HH; ++h)
            vw[bn * HH * WW + h * WW + w] = expf(slog[h][t] - m) * inv;
    }
}

// ---------------- K3: depth softmax * vert_w summed over H -> dp bf16 [b][k][128] ----------------
__global__ __launch_bounds__(256) void k3_depth(const float* __restrict__ dl,
                                                const float* __restrict__ vw,
                                                __bf16* __restrict__ dp_g) {
    int bx = blockIdx.x;
    int bn = bx / WW;
    int w  = bx % WW;
    __shared__ float sl[HH][DD];
    int t = threadIdx.x;
    for (int e = t; e < HH * DD; e += 256) {
        int d = e % DD, h = e / DD;
        sl[h][d] = dl[((bn * DD + d) * HH + h) * WW + w];
    }
    __syncthreads();
    int g = t >> 4;
    int l = t & 15;
    float v[7];
#pragma unroll
    for (int j = 0; j < 7; ++j) v[j] = sl[g][l + 16 * j];
    float m = v[0];
#pragma unroll
    for (int j = 1; j < 7; ++j) m = fmaxf(m, v[j]);
#pragma unroll
    for (int mk = 1; mk < 16; mk <<= 1) m = fmaxf(m, __shfl_xor(m, mk, 64));
    float s = 0.f;
#pragma unroll
    for (int j = 0; j < 7; ++j) { v[j] = expf(v[j] - m); s += v[j]; }
#pragma unroll
    for (int mk = 1; mk < 16; mk <<= 1) s += __shfl_xor(s, mk, 64);
    float wv = vw[bn * HH * WW + g * WW + w] / s;
#pragma unroll
    for (int j = 0; j < 7; ++j) sl[g][l + 16 * j] = v[j] * wv;
    __syncthreads();
    if (t < DD) {
        float acc = 0.f;
#pragma unroll
        for (int h = 0; h < HH; ++h) acc += sl[h][t];
        int b = bn / NCAM, n = bn % NCAM;
        int k = n * WW + w;
        dp_g[(size_t)b * (KPAD * DPAD) + k * DPAD + t] = (__bf16)acc;
    }
}

// ---------------- K4: feat max over H -> fpT bf16 [b][c][288] ----------------
__global__ __launch_bounds__(256) void k4_featmax(const float* __restrict__ feat,
                                                  __bf16* __restrict__ fpT_g) {
    int tid = blockIdx.x * 256 + threadIdx.x;
    if (tid >= BN * CF * WW) return;
    int bn = tid / (CF * WW);
    int r  = tid % (CF * WW);
    int c = r / WW, w = r % WW;
    float m = -1e30f;
    for (int h = 0; h < HH; ++h)
        m = fmaxf(m, feat[((bn * CF + c) * HH + h) * WW + w]);
    int b = bn / NCAM, n = bn % NCAM;
    fpT_g[(size_t)b * (CF * KPAD) + c * KPAD + n * WW + w] = (__bf16)m;
}

// ---------------- K5: fused MatrixVT projection via MFMA bf16 ----------------
// block = (b, 64-v tile): 4*256 = 1024 blocks, 256 threads (4 waves).
__global__ __launch_bounds__(256, 2) void k5_bev(const __bf16* __restrict__ dp_g,
                                                 const __bf16* __restrict__ fpT_g,
                                                 const float* __restrict__ circle,
                                                 const float* __restrict__ ray,
                                                 float* __restrict__ out) {
    int b  = blockIdx.x >> 8;
    int vt = blockIdx.x & 255;
    int v0 = vt * VT;
    __shared__ __align__(16) __bf16 circleT[VT][136];  // [v][d], d 112..127 zero
    __shared__ __align__(16) __bf16 dps[KC][136];      // [k][d]
    __shared__ __align__(16) __bf16 plds[VT][104];     // [v][k]
    __shared__ __align__(16) __bf16 fts[CF][104];      // [c][k]
    int t = threadIdx.x;
    int wv = t >> 6;
    int lane = t & 63;
    int r16 = lane & 15;
    int kg4 = lane >> 4;

    // stage circle tile (transpose, f32->bf16)
    const float* cb = circle + (size_t)b * DD * XY + v0;
    for (int e = t; e < DD * (VT / 4); e += 256) {
        int d = e >> 4, vq = e & 15;
        float4 cv = *(const float4*)&cb[(size_t)d * XY + vq * 4];
        circleT[vq * 4 + 0][d] = (__bf16)cv.x;
        circleT[vq * 4 + 1][d] = (__bf16)cv.y;
        circleT[vq * 4 + 2][d] = (__bf16)cv.z;
        circleT[vq * 4 + 3][d] = (__bf16)cv.w;
    }
    for (int e = t; e < VT * 16; e += 256) {
        int v = e >> 4, d = DD + (e & 15);
        circleT[v][d] = (__bf16)0.f;
    }

    f32x4 acc[5];
#pragma unroll
    for (int n = 0; n < 5; ++n) acc[n] = (f32x4){0.f, 0.f, 0.f, 0.f};

    const __bf16* dpb = dp_g + (size_t)b * (KPAD * DPAD);
    const __bf16* ftb = fpT_g + (size_t)b * (CF * KPAD);
    const float* rayb = ray + (size_t)b * KTOT * XY + v0;
    int vloc = wv * 16 + kg4 * 4;

    for (int cc = 0; cc < 3; ++cc) {
        int k0 = cc * KC;
        __syncthreads();   // protect prev-chunk LDS reads
        // stage dp chunk [96][128]
        for (int e = t; e < KC * 16; e += 256) {
            int kk = e >> 4, dg = e & 15;
            uint4 u = *(const uint4*)(dpb + (size_t)(k0 + kk) * DPAD + dg * 8);
            *(uint4*)&dps[kk][dg * 8] = u;
        }
        // stage fpT chunk [80][96]
        for (int e = t; e < CF * 12; e += 256) {
            int c = e / 12, kg = e % 12;
            uint4 u = *(const uint4*)(ftb + (size_t)c * KPAD + k0 + kg * 8);
            *(uint4*)&fts[c][kg * 8] = u;
        }
        __syncthreads();

        // GEMM1: P[v][k] = sum_d circleT[v][d] * dp[k][d]
        f32x4 pc[6];
#pragma unroll
        for (int n = 0; n < 6; ++n) pc[n] = (f32x4){0.f, 0.f, 0.f, 0.f};
#pragma unroll
        for (int ks = 0; ks < 4; ++ks) {
            bf16x8 af = *(const bf16x8*)&circleT[wv * 16 + r16][ks * 32 + kg4 * 8];
#pragma unroll
            for (int n = 0; n < 6; ++n) {
                bf16x8 bf = *(const bf16x8*)&dps[n * 16 + r16][ks * 32 + kg4 * 8];
                pc[n] = __builtin_amdgcn_mfma_f32_16x16x32_bf16(af, bf, pc[n], 0, 0, 0);
            }
        }
        // apply ray and write P (bf16) to plds[v][k]
#pragma unroll
        for (int n = 0; n < 6; ++n) {
            int k = k0 + n * 16 + r16;
            float4 rv = {0.f, 0.f, 0.f, 0.f};
            if (k < KTOT) rv = *(const float4*)&rayb[(size_t)k * XY + vloc];
            float rvv[4] = {rv.x, rv.y, rv.z, rv.w};
#pragma unroll
            for (int j = 0; j < 4; ++j)
                plds[vloc + j][n * 16 + r16] = (__bf16)(pc[n][j] * rvv[j]);
        }
        __syncthreads();

        // GEMM2: bev[v][c] += P[v][kc] * fpT[c][kc]
#pragma unroll
        for (int ks = 0; ks < 3; ++ks) {
            bf16x8 a2 = *(const bf16x8*)&plds[wv * 16 + r16][ks * 32 + kg4 * 8];
#pragma unroll
            for (int n = 0; n < 5; ++n) {
                bf16x8 b2 = *(const bf16x8*)&fts[n * 16 + r16][ks * 32 + kg4 * 8];
                acc[n] = __builtin_amdgcn_mfma_f32_16x16x32_bf16(a2, b2, acc[n], 0, 0, 0);
            }
        }
    }

    // epilogue: out[b][c][v0 + vloc .. +3]
    float* ob = out + (size_t)b * CF * XY + v0 + vloc;
#pragma unroll
    for (int n = 0; n < 5; ++n) {
        int c = n * 16 + r16;
        *(float4*)&ob[(size_t)c * XY] = *(float4*)&acc[n];
    }
}

extern "C" void kernel_launch(void* const* d_in, const int* in_sizes, int n_in,
                              void* d_out, int out_size, void* d_ws, size_t ws_size,
                              hipStream_t stream) {
    const float* feat   = (const float*)d_in[0];
    const float* dl     = (const float*)d_in[1];
    const float* circle = (const float*)d_in[2];
    const float* ray    = (const float*)d_in[3];
    const float* w1     = (const float*)d_in[4];
    const float* b1     = (const float*)d_in[5];
    const float* w2     = (const float*)d_in[6];
    const float* b2     = (const float*)d_in[7];
    float* out = (float*)d_out;

    // ws layout: bf16 region first (memset to 0 for padding), then f32 buffers
    __bf16* dp_g  = (__bf16*)d_ws;                     // 4*288*128 = 147456
    __bf16* fpT_g = dp_g + BATCH * KPAD * DPAD;        // 4*80*288  =  92160
    size_t bf16_bytes = (size_t)(BATCH * KPAD * DPAD + BATCH * CF * KPAD) * 2;  // 479232
    float* hbuf = (float*)((char*)d_ws + bf16_bytes);  // 24*64*16*44
    float* vw   = hbuf + BN * C2 * HH * WW;

    hipMemsetAsync(d_ws, 0, bf16_bytes, stream);
    hipLaunchKernelGGL(k1_conv1, dim3(384), dim3(256), 0, stream, feat, w1, b1, hbuf);
    hipLaunchKernelGGL(k2_vertw, dim3(96), dim3(256), 0, stream, hbuf, w2, b2, vw);
    hipLaunchKernelGGL(k3_depth, dim3(BN * WW), dim3(256), 0, stream, dl, vw, dp_g);
    hipLaunchKernelGGL(k4_featmax, dim3((BN * CF * WW + 255) / 256), dim3(256), 0, stream, feat, fpT_g);
    hipLaunchKernelGGL(k5_bev, dim3(BATCH * (XY / VT)), dim3(256), 0, stream, dp_g, fpT_g, circle, ray, out);
}

// Round 3
// 256.084 us; speedup vs baseline: 1.9339x; 1.2628x over previous
//
#include <hip/hip_runtime.h>
#include <hip/hip_bf16.h>

#define BN 24
#define BATCH 4
#define NCAM 6
#define CF 80
#define C2 64
#define DD 112
#define HH 16
#define WW 44
#define KTOT 264
#define KPAD 288
#define DPAD 128
#define XY 16384
#define VT 64
#define KC 96
#define CIP 96   /* ci padded to 3 K-steps of 32 for conv1 GEMM */

typedef __bf16 bf16x8 __attribute__((ext_vector_type(8)));
typedef float f32x4 __attribute__((ext_vector_type(4)));

// ---------------- K0: prepack conv1 weights -> wpk[kykx][co][ci96] bf16 ----------------
__global__ __launch_bounds__(256) void k0_prepack(const float* __restrict__ w1,
                                                  __bf16* __restrict__ wpk) {
    int e = blockIdx.x * 256 + threadIdx.x;
    if (e >= 9 * C2 * CIP) return;
    int kk = e / (C2 * CIP);
    int r  = e % (C2 * CIP);
    int co = r / CIP;
    int ci = r % CIP;
    float v = 0.f;
    if (ci < CF) v = w1[((co * CF + ci) * 3 + kk / 3) * 3 + kk % 3];
    wpk[e] = (__bf16)v;
}

// ---------------- K1: conv3x3(80->64)+ReLU as 9 accumulated MFMA GEMMs ----------------
// block = (bn, h-pair): 24*8 = 192 blocks, 256 threads (4 waves).
// M = 2 rows x 44 w = 88 pixels (padded to 96 = 6 tiles of 16), N = 64 co, K = 96 ci (pad).
__global__ __launch_bounds__(256) void k1_conv1(const float* __restrict__ feat,
                                                const __bf16* __restrict__ wpk,
                                                const float* __restrict__ b1,
                                                float* __restrict__ hbuf) {
    int bn = blockIdx.x >> 3;
    int hq = blockIdx.x & 7;
    int h0 = hq * 2;
    __shared__ __bf16 fsl[5][48][CIP];   // [yl][x][ci]: y = h0+yl-1 (row 4 = zero pad)
    __shared__ __bf16 wlds[C2][CIP];     // [co][ci] for current (ky,kx)
    int t = threadIdx.x;

    // zero the slab, then fill real values
    uint4 zz = make_uint4(0, 0, 0, 0);
    uint4* fz = (uint4*)&fsl[0][0][0];
    for (int e = t; e < 5 * 48 * CIP * 2 / 16; e += 256) fz[e] = zz;
    __syncthreads();
    for (int e = t; e < CF * 4 * WW; e += 256) {
        int ci = e / (4 * WW);
        int r  = e % (4 * WW);
        int yl = r / WW;
        int w  = r % WW;
        int y = h0 + yl - 1;
        if (y >= 0 && y < HH)
            fsl[yl][w + 1][ci] = (__bf16)feat[((bn * CF + ci) * HH + y) * WW + w];
    }

    int wave = t >> 6, lane = t & 63, r16 = lane & 15, kg4 = lane >> 4;
    int nt = (wave < 2) ? 2 : 1;     // 6 M-tiles: wave0:{0,4} w1:{1,5} w2:{2} w3:{3}
    int hlA[2], wA[2];
#pragma unroll
    for (int i = 0; i < 2; ++i) {
        int p = (wave + 4 * i) * 16 + r16;    // pixel row for A-frag
        hlA[i] = p / WW;
        wA[i]  = p % WW;
    }
    f32x4 acc[2][4];
#pragma unroll
    for (int i = 0; i < 2; ++i)
#pragma unroll
        for (int n = 0; n < 4; ++n) acc[i][n] = (f32x4){0.f, 0.f, 0.f, 0.f};

    for (int kk = 0; kk < 9; ++kk) {
        int ky = kk / 3, kx = kk % 3;
        __syncthreads();   // protect wlds readers of prev tap (also covers fsl fill on kk=0)
        {
            const uint4* wsrc = (const uint4*)(wpk + kk * C2 * CIP);
            uint4* wdst = (uint4*)&wlds[0][0];
            for (int e = t; e < C2 * CIP / 8; e += 256) wdst[e] = wsrc[e];
        }
        __syncthreads();
#pragma unroll
        for (int ks = 0; ks < 3; ++ks) {
            bf16x8 bf[4];
#pragma unroll
            for (int n = 0; n < 4; ++n)
                bf[n] = *(const bf16x8*)&wlds[n * 16 + r16][ks * 32 + kg4 * 8];
            for (int i = 0; i < nt; ++i) {
                bf16x8 af = *(const bf16x8*)&fsl[hlA[i] + ky][wA[i] + kx][ks * 32 + kg4 * 8];
#pragma unroll
                for (int n = 0; n < 4; ++n)
                    acc[i][n] = __builtin_amdgcn_mfma_f32_16x16x32_bf16(af, bf[n], acc[i][n], 0, 0, 0);
            }
        }
    }

    // epilogue: bias + ReLU, store f32 hbuf[bn][h][w][co]
    for (int i = 0; i < nt; ++i) {
        int mt = wave + 4 * i;
#pragma unroll
        for (int n = 0; n < 4; ++n) {
            int co = n * 16 + r16;
            float bias = b1[co];
#pragma unroll
            for (int j = 0; j < 4; ++j) {
                int p = mt * 16 + kg4 * 4 + j;   // pixel row for C-frag
                if (p < 2 * WW) {
                    int hl = p / WW, w = p % WW;
                    float v = acc[i][n][j] + bias;
                    v = fmaxf(v, 0.f);
                    hbuf[((size_t)(bn * HH + h0 + hl) * WW + w) * C2 + co] = v;
                }
            }
        }
    }
}

// ---------------- K2a: conv3x3(64->1) logits, parallel over (bn,h) ----------------
__global__ __launch_bounds__(256) void k2a_logits(const float* __restrict__ hbuf,
                                                  const float* __restrict__ w2,
                                                  const float* __restrict__ b2,
                                                  float* __restrict__ lg) {
    int bn = blockIdx.x >> 4;
    int h  = blockIdx.x & 15;
    __shared__ float w2t[9][C2];
    __shared__ float pr[4][WW];
    int t = threadIdx.x;
    for (int e = t; e < 9 * C2; e += 256) {
        int kk = e % 9, ci = e / 9;
        w2t[kk][ci] = w2[ci * 9 + kk];
    }
    __syncthreads();
    int w = t & 63;
    int g = t >> 6;     // ci-group of 16
    float acc = 0.f;
    if (w < WW) {
#pragma unroll
        for (int ky = 0; ky < 3; ++ky) {
            int y = h + ky - 1;
            if (y < 0 || y >= HH) continue;
#pragma unroll
            for (int kx = 0; kx < 3; ++kx) {
                int x = w + kx - 1;
                if (x < 0 || x >= WW) continue;
                const float* hp = hbuf + ((size_t)(bn * HH + y) * WW + x) * C2 + g * 16;
                const float* wp = &w2t[ky * 3 + kx][g * 16];
#pragma unroll
                for (int q = 0; q < 4; ++q) {
                    f32x4 hv = *(const f32x4*)(hp + q * 4);
                    acc += wp[q * 4 + 0] * hv[0] + wp[q * 4 + 1] * hv[1]
                         + wp[q * 4 + 2] * hv[2] + wp[q * 4 + 3] * hv[3];
                }
            }
        }
        pr[g][w] = acc;
    }
    __syncthreads();
    if (t < WW) {
        float s = b2[0] + pr[0][t] + pr[1][t] + pr[2][t] + pr[3][t];
        lg[(bn * HH + h) * WW + t] = s;
    }
}

// ---------------- K2b: softmax over H -> vert weights ----------------
__global__ __launch_bounds__(64) void k2b_softmaxh(const float* __restrict__ lg,
                                                   float* __restrict__ vw) {
    int bn = blockIdx.x;
    int w  = threadIdx.x;
    if (w >= WW) return;
    float r[HH];
    float m = -1e30f;
#pragma unroll
    for (int h = 0; h < HH; ++h) {
        r[h] = lg[(bn * HH + h) * WW + w];
        m = fmaxf(m, r[h]);
    }
    float s = 0.f;
#pragma unroll
    for (int h = 0; h < HH; ++h) { r[h] = expf(r[h] - m); s += r[h]; }
    float inv = 1.f / s;
#pragma unroll
    for (int h = 0; h < HH; ++h)
        vw[(bn * HH + h) * WW + w] = r[h] * inv;
}

// ---------------- K3: depth softmax * vert_w summed over H -> dp bf16 [b][k][128] ----------------
__global__ __launch_bounds__(256) void k3_depth(const float* __restrict__ dl,
                                                const float* __restrict__ vw,
                                                __bf16* __restrict__ dp_g) {
    int bx = blockIdx.x;
    int bn = bx / WW;
    int w  = bx % WW;
    __shared__ float sl[HH][DD];
    int t = threadIdx.x;
    for (int e = t; e < HH * DD; e += 256) {
        int d = e % DD, h = e / DD;
        sl[h][d] = dl[((bn * DD + d) * HH + h) * WW + w];
    }
    __syncthreads();
    int g = t >> 4;
    int l = t & 15;
    float v[7];
#pragma unroll
    for (int j = 0; j < 7; ++j) v[j] = sl[g][l + 16 * j];
    float m = v[0];
#pragma unroll
    for (int j = 1; j < 7; ++j) m = fmaxf(m, v[j]);
#pragma unroll
    for (int mk = 1; mk < 16; mk <<= 1) m = fmaxf(m, __shfl_xor(m, mk, 64));
    float s = 0.f;
#pragma unroll
    for (int j = 0; j < 7; ++j) { v[j] = expf(v[j] - m); s += v[j]; }
#pragma unroll
    for (int mk = 1; mk < 16; mk <<= 1) s += __shfl_xor(s, mk, 64);
    float wv = vw[bn * HH * WW + g * WW + w] / s;
#pragma unroll
    for (int j = 0; j < 7; ++j) sl[g][l + 16 * j] = v[j] * wv;
    __syncthreads();
    if (t < DD) {
        float acc = 0.f;
#pragma unroll
        for (int h = 0; h < HH; ++h) acc += sl[h][t];
        int b = bn / NCAM, n = bn % NCAM;
        int k = n * WW + w;
        dp_g[(size_t)b * (KPAD * DPAD) + k * DPAD + t] = (__bf16)acc;
    }
}

// ---------------- K4: feat max over H -> fpT bf16 [b][c][288] ----------------
__global__ __launch_bounds__(256) void k4_featmax(const float* __restrict__ feat,
                                                  __bf16* __restrict__ fpT_g) {
    int tid = blockIdx.x * 256 + threadIdx.x;
    if (tid >= BN * CF * WW) return;
    int bn = tid / (CF * WW);
    int r  = tid % (CF * WW);
    int c = r / WW, w = r % WW;
    float m = -1e30f;
    for (int h = 0; h < HH; ++h)
        m = fmaxf(m, feat[((bn * CF + c) * HH + h) * WW + w]);
    int b = bn / NCAM, n = bn % NCAM;
    fpT_g[(size_t)b * (CF * KPAD) + c * KPAD + n * WW + w] = (__bf16)m;
}

// ---------------- K5: fused MatrixVT projection via MFMA bf16 ----------------
__global__ __launch_bounds__(256, 2) void k5_bev(const __bf16* __restrict__ dp_g,
                                                 const __bf16* __restrict__ fpT_g,
                                                 const float* __restrict__ circle,
                                                 const float* __restrict__ ray,
                                                 float* __restrict__ out) {
    int b  = blockIdx.x >> 8;
    int vt = blockIdx.x & 255;
    int v0 = vt * VT;
    __shared__ __align__(16) __bf16 circleT[VT][136];
    __shared__ __align__(16) __bf16 dps[KC][136];
    __shared__ __align__(16) __bf16 plds[VT][104];
    __shared__ __align__(16) __bf16 fts[CF][104];
    int t = threadIdx.x;
    int wv = t >> 6;
    int lane = t & 63;
    int r16 = lane & 15;
    int kg4 = lane >> 4;

    const float* cb = circle + (size_t)b * DD * XY + v0;
    for (int e = t; e < DD * (VT / 4); e += 256) {
        int d = e >> 4, vq = e & 15;
        float4 cv = *(const float4*)&cb[(size_t)d * XY + vq * 4];
        circleT[vq * 4 + 0][d] = (__bf16)cv.x;
        circleT[vq * 4 + 1][d] = (__bf16)cv.y;
        circleT[vq * 4 + 2][d] = (__bf16)cv.z;
        circleT[vq * 4 + 3][d] = (__bf16)cv.w;
    }
    for (int e = t; e < VT * 16; e += 256) {
        int v = e >> 4, d = DD + (e & 15);
        circleT[v][d] = (__bf16)0.f;
    }

    f32x4 acc[5];
#pragma unroll
    for (int n = 0; n < 5; ++n) acc[n] = (f32x4){0.f, 0.f, 0.f, 0.f};

    const __bf16* dpb = dp_g + (size_t)b * (KPAD * DPAD);
    const __bf16* ftb = fpT_g + (size_t)b * (CF * KPAD);
    const float* rayb = ray + (size_t)b * KTOT * XY + v0;
    int vloc = wv * 16 + kg4 * 4;

    for (int cc = 0; cc < 3; ++cc) {
        int k0 = cc * KC;
        __syncthreads();
        for (int e = t; e < KC * 16; e += 256) {
            int kk = e >> 4, dg = e & 15;
            uint4 u = *(const uint4*)(dpb + (size_t)(k0 + kk) * DPAD + dg * 8);
            *(uint4*)&dps[kk][dg * 8] = u;
        }
        for (int e = t; e < CF * 12; e += 256) {
            int c = e / 12, kg = e % 12;
            uint4 u = *(const uint4*)(ftb + (size_t)c * KPAD + k0 + kg * 8);
            *(uint4*)&fts[c][kg * 8] = u;
        }
        __syncthreads();

        f32x4 pc[6];
#pragma unroll
        for (int n = 0; n < 6; ++n) pc[n] = (f32x4){0.f, 0.f, 0.f, 0.f};
#pragma unroll
        for (int ks = 0; ks < 4; ++ks) {
            bf16x8 af = *(const bf16x8*)&circleT[wv * 16 + r16][ks * 32 + kg4 * 8];
#pragma unroll
            for (int n = 0; n < 6; ++n) {
                bf16x8 bfv = *(const bf16x8*)&dps[n * 16 + r16][ks * 32 + kg4 * 8];
                pc[n] = __builtin_amdgcn_mfma_f32_16x16x32_bf16(af, bfv, pc[n], 0, 0, 0);
            }
        }
#pragma unroll
        for (int n = 0; n < 6; ++n) {
            int k = k0 + n * 16 + r16;
            float4 rv = {0.f, 0.f, 0.f, 0.f};
            if (k < KTOT) rv = *(const float4*)&rayb[(size_t)k * XY + vloc];
            float rvv[4] = {rv.x, rv.y, rv.z, rv.w};
#pragma unroll
            for (int j = 0; j < 4; ++j)
                plds[vloc + j][n * 16 + r16] = (__bf16)(pc[n][j] * rvv[j]);
        }
        __syncthreads();

#pragma unroll
        for (int ks = 0; ks < 3; ++ks) {
            bf16x8 a2 = *(const bf16x8*)&plds[wv * 16 + r16][ks * 32 + kg4 * 8];
#pragma unroll
            for (int n = 0; n < 5; ++n) {
                bf16x8 b2v = *(const bf16x8*)&fts[n * 16 + r16][ks * 32 + kg4 * 8];
                acc[n] = __builtin_amdgcn_mfma_f32_16x16x32_bf16(a2, b2v, acc[n], 0, 0, 0);
            }
        }
    }

    float* ob = out + (size_t)b * CF * XY + v0 + vloc;
#pragma unroll
    for (int n = 0; n < 5; ++n) {
        int c = n * 16 + r16;
        *(float4*)&ob[(size_t)c * XY] = *(float4*)&acc[n];
    }
}

extern "C" void kernel_launch(void* const* d_in, const int* in_sizes, int n_in,
                              void* d_out, int out_size, void* d_ws, size_t ws_size,
                              hipStream_t stream) {
    const float* feat   = (const float*)d_in[0];
    const float* dl     = (const float*)d_in[1];
    const float* circle = (const float*)d_in[2];
    const float* ray    = (const float*)d_in[3];
    const float* w1     = (const float*)d_in[4];
    const float* b1     = (const float*)d_in[5];
    const float* w2     = (const float*)d_in[6];
    const float* b2     = (const float*)d_in[7];
    float* out = (float*)d_out;

    __bf16* dp_g  = (__bf16*)d_ws;                        // 4*288*128 = 147456
    __bf16* fpT_g = dp_g + BATCH * KPAD * DPAD;           // 4*80*288  =  92160
    size_t bf16_bytes = (size_t)(BATCH * KPAD * DPAD + BATCH * CF * KPAD) * 2;  // 479232
    float* hbuf = (float*)((char*)d_ws + bf16_bytes);     // 24*16*44*64 f32 (NHWC)
    float* lg   = hbuf + (size_t)BN * HH * WW * C2;       // 16896
    float* vw   = lg + BN * HH * WW;                      // 16896
    __bf16* wpk = (__bf16*)(vw + BN * HH * WW);           // 9*64*96 = 55296

    hipMemsetAsync(d_ws, 0, bf16_bytes, stream);
    hipLaunchKernelGGL(k0_prepack, dim3(216), dim3(256), 0, stream, w1, wpk);
    hipLaunchKernelGGL(k1_conv1, dim3(192), dim3(256), 0, stream, feat, wpk, b1, hbuf);
    hipLaunchKernelGGL(k2a_logits, dim3(384), dim3(256), 0, stream, hbuf, w2, b2, lg);
    hipLaunchKernelGGL(k2b_softmaxh, dim3(24), dim3(64), 0, stream, lg, vw);
    hipLaunchKernelGGL(k3_depth, dim3(BN * WW), dim3(256), 0, stream, dl, vw, dp_g);
    hipLaunchKernelGGL(k4_featmax, dim3((BN * CF * WW + 255) / 256), dim3(256), 0, stream, feat, fpT_g);
    hipLaunchKernelGGL(k5_bev, dim3(BATCH * (XY / VT)), dim3(256), 0, stream, dp_g, fpT_g, circle, ray, out);
}

// Round 4
// 208.374 us; speedup vs baseline: 2.3766x; 1.2290x over previous
//
#include <hip/hip_runtime.h>
#include <hip/hip_bf16.h>

#define BN 24
#define BATCH 4
#define NCAM 6
#define CF 80
#define C2 64
#define DD 112
#define HH 16
#define WW 44
#define KTOT 264
#define KPAD 288
#define DPAD 128
#define XY 16384
#define VT 64
#define KC 96
#define CIP 96   /* ci padded to 3 K-steps of 32 for conv1 GEMM */

typedef __bf16 bf16x8 __attribute__((ext_vector_type(8)));
typedef float f32x4 __attribute__((ext_vector_type(4)));

static __device__ inline unsigned pk2bf(float a, float b) {
    __bf16 x = (__bf16)a, y = (__bf16)b;
    unsigned short ux = __builtin_bit_cast(unsigned short, x);
    unsigned short uy = __builtin_bit_cast(unsigned short, y);
    return (unsigned)ux | ((unsigned)uy << 16);
}

// ---------------- K0: prepack conv1 weights into per-lane fragment order ----------------
// wpk[(((kk*3+ks)*4+kg4)*64 + co)*8 + j] = w1[co][ci=ks*32+kg4*8+j][ky][kx]  (0 for ci>=80)
__global__ __launch_bounds__(256) void k0_prepack(const float* __restrict__ w1,
                                                  __bf16* __restrict__ wpk) {
    int e = blockIdx.x * 256 + threadIdx.x;
    if (e >= 9 * C2 * CIP) return;
    int kk = e / (C2 * CIP);
    int r  = e % (C2 * CIP);
    int co = r / CIP;
    int ci = r % CIP;
    float v = 0.f;
    if (ci < CF) v = w1[((co * CF + ci) * 3 + kk / 3) * 3 + kk % 3];
    int ks = ci >> 5, kg4 = (ci >> 3) & 3, j = ci & 7;
    wpk[(size_t)((((kk * 3 + ks) * 4 + kg4) * C2 + co) * 8 + j)] = (__bf16)v;
}

// ---------------- K1 v2: conv3x3(80->64)+ReLU, barrier-free MFMA main loop ----------------
// block = (bn, h): 384 blocks, 256 threads (4 waves). M=48 pixels (3 tiles), N=64 (wave owns 16).
__global__ __launch_bounds__(256) void k1_conv1(const float* __restrict__ feat,
                                                const __bf16* __restrict__ wpk,
                                                const float* __restrict__ b1,
                                                float* __restrict__ hbuf) {
    int bn = blockIdx.x >> 4;
    int h  = blockIdx.x & 15;
    __shared__ __bf16 fsl[3][52][104];   // [yl][x=w+1][ci]; 32448 B, zero-padded
    int t = threadIdx.x;

    uint4 zz = make_uint4(0, 0, 0, 0);
    uint4* fz = (uint4*)&fsl[0][0][0];
    for (int e = t; e < 3 * 52 * 104 * 2 / 16; e += 256) fz[e] = zz;
    __syncthreads();
    // lane = consecutive ci -> conflict-free LDS writes; global 16B scatter absorbed by L2
    for (int e = t; e < CF * 3 * 11; e += 256) {
        int ci = e % CF;
        int r  = e / CF;
        int yl = r % 3;
        int q  = r / 3;
        int y = h + yl - 1;
        if (y >= 0 && y < HH) {
            float4 f = *(const float4*)&feat[((bn * CF + ci) * HH + y) * WW + q * 4];
            fsl[yl][q * 4 + 1][ci] = (__bf16)f.x;
            fsl[yl][q * 4 + 2][ci] = (__bf16)f.y;
            fsl[yl][q * 4 + 3][ci] = (__bf16)f.z;
            fsl[yl][q * 4 + 4][ci] = (__bf16)f.w;
        }
    }
    __syncthreads();

    int wave = t >> 6, lane = t & 63, r16 = lane & 15, kg4 = lane >> 4;
    f32x4 acc[3];
#pragma unroll
    for (int m = 0; m < 3; ++m) acc[m] = (f32x4){0.f, 0.f, 0.f, 0.f};

#pragma unroll
    for (int ky = 0; ky < 3; ++ky) {
#pragma unroll
        for (int kx = 0; kx < 3; ++kx) {
            int kk = ky * 3 + kx;
#pragma unroll
            for (int ks = 0; ks < 3; ++ks) {
                bf16x8 bw = *(const bf16x8*)(wpk +
                    (size_t)((((kk * 3 + ks) * 4 + kg4) * C2 + wave * 16 + r16) * 8));
#pragma unroll
                for (int m = 0; m < 3; ++m) {
                    bf16x8 af = *(const bf16x8*)&fsl[ky][m * 16 + r16 + kx][ks * 32 + kg4 * 8];
                    acc[m] = __builtin_amdgcn_mfma_f32_16x16x32_bf16(af, bw, acc[m], 0, 0, 0);
                }
            }
        }
    }

    int co = wave * 16 + r16;
    float bias = b1[co];
#pragma unroll
    for (int m = 0; m < 3; ++m) {
#pragma unroll
        for (int j = 0; j < 4; ++j) {
            int p = m * 16 + kg4 * 4 + j;
            if (p < WW) {
                float v = fmaxf(acc[m][j] + bias, 0.f);
                hbuf[((size_t)(bn * HH + h) * WW + p) * C2 + co] = v;
            }
        }
    }
}

// ---------------- K2a: conv3x3(64->1) logits ----------------
__global__ __launch_bounds__(256) void k2a_logits(const float* __restrict__ hbuf,
                                                  const float* __restrict__ w2,
                                                  const float* __restrict__ b2,
                                                  float* __restrict__ lg) {
    int bn = blockIdx.x >> 4;
    int h  = blockIdx.x & 15;
    __shared__ float w2t[9][C2];
    __shared__ float pr[4][WW];
    int t = threadIdx.x;
    for (int e = t; e < 9 * C2; e += 256) {
        int kk = e % 9, ci = e / 9;
        w2t[kk][ci] = w2[ci * 9 + kk];
    }
    __syncthreads();
    int w = t & 63;
    int g = t >> 6;
    float acc = 0.f;
    if (w < WW) {
#pragma unroll
        for (int ky = 0; ky < 3; ++ky) {
            int y = h + ky - 1;
            if (y < 0 || y >= HH) continue;
#pragma unroll
            for (int kx = 0; kx < 3; ++kx) {
                int x = w + kx - 1;
                if (x < 0 || x >= WW) continue;
                const float* hp = hbuf + ((size_t)(bn * HH + y) * WW + x) * C2 + g * 16;
                const float* wp = &w2t[ky * 3 + kx][g * 16];
#pragma unroll
                for (int q = 0; q < 4; ++q) {
                    f32x4 hv = *(const f32x4*)(hp + q * 4);
                    acc += wp[q * 4 + 0] * hv[0] + wp[q * 4 + 1] * hv[1]
                         + wp[q * 4 + 2] * hv[2] + wp[q * 4 + 3] * hv[3];
                }
            }
        }
        pr[g][w] = acc;
    }
    __syncthreads();
    if (t < WW) {
        float s = b2[0] + pr[0][t] + pr[1][t] + pr[2][t] + pr[3][t];
        lg[(bn * HH + h) * WW + t] = s;
    }
}

// ---------------- K2b: softmax over H -> vert weights ----------------
__global__ __launch_bounds__(64) void k2b_softmaxh(const float* __restrict__ lg,
                                                   float* __restrict__ vw) {
    int bn = blockIdx.x;
    int w  = threadIdx.x;
    if (w >= WW) return;
    float r[HH];
    float m = -1e30f;
#pragma unroll
    for (int h = 0; h < HH; ++h) {
        r[h] = lg[(bn * HH + h) * WW + w];
        m = fmaxf(m, r[h]);
    }
    float s = 0.f;
#pragma unroll
    for (int h = 0; h < HH; ++h) { r[h] = expf(r[h] - m); s += r[h]; }
    float inv = 1.f / s;
#pragma unroll
    for (int h = 0; h < HH; ++h)
        vw[(bn * HH + h) * WW + w] = r[h] * inv;
}

// ---------------- K3a: per-(bn,h) depth softmax * vw -> part[bn][h][w][d] bf16 ----------------
__global__ __launch_bounds__(256) void k3a_depth(const float* __restrict__ dl,
                                                 const float* __restrict__ vw,
                                                 __bf16* __restrict__ part) {
    int bn = blockIdx.x >> 4;
    int h  = blockIdx.x & 15;
    __shared__ float slT[WW][117];   // [w][d], pad 117 breaks bank patterns
    int t = threadIdx.x;
    // coalesced load of the [112][44] plane, transposed into LDS
    for (int e = t; e < DD * 11; e += 256) {
        int d = e / 11, q = e % 11;
        float4 f = *(const float4*)&dl[((size_t)(bn * DD + d) * HH + h) * WW + q * 4];
        slT[q * 4 + 0][d] = f.x;
        slT[q * 4 + 1][d] = f.y;
        slT[q * 4 + 2][d] = f.z;
        slT[q * 4 + 3][d] = f.w;
    }
    __syncthreads();
    if (t < 4 * WW) {
        int w = t >> 2, l = t & 3;
        float v[28];
#pragma unroll
        for (int i = 0; i < 28; ++i) v[i] = slT[w][l + 4 * i];
        float m = v[0];
#pragma unroll
        for (int i = 1; i < 28; ++i) m = fmaxf(m, v[i]);
        m = fmaxf(m, __shfl_xor(m, 1, 64));
        m = fmaxf(m, __shfl_xor(m, 2, 64));
        float s = 0.f;
#pragma unroll
        for (int i = 0; i < 28; ++i) { v[i] = __expf(v[i] - m); s += v[i]; }
        s += __shfl_xor(s, 1, 64);
        s += __shfl_xor(s, 2, 64);
        float scale = vw[(bn * HH + h) * WW + w] / s;
#pragma unroll
        for (int i = 0; i < 28; ++i) slT[w][l + 4 * i] = v[i] * scale;
    }
    __syncthreads();
    // coalesced bf16 pack-out: part[bn][h][w][d]
    __bf16* pb = part + ((size_t)(bn * HH + h) * WW) * DD;
    for (int e = t; e < WW * 14; e += 256) {
        int w = e / 14, dg = e % 14;
        uint4 u;
        u.x = pk2bf(slT[w][dg * 8 + 0], slT[w][dg * 8 + 1]);
        u.y = pk2bf(slT[w][dg * 8 + 2], slT[w][dg * 8 + 3]);
        u.z = pk2bf(slT[w][dg * 8 + 4], slT[w][dg * 8 + 5]);
        u.w = pk2bf(slT[w][dg * 8 + 6], slT[w][dg * 8 + 7]);
        *(uint4*)(pb + (size_t)w * DD + dg * 8) = u;
    }
}

// ---------------- K3b: sum part over h -> dp bf16 [b][k][128] ----------------
__global__ __launch_bounds__(256) void k3b_hsum(const __bf16* __restrict__ part,
                                                __bf16* __restrict__ dp_g) {
    int bn = blockIdx.x >> 2;
    int wq = blockIdx.x & 3;
    int b = bn / NCAM, n = bn % NCAM;
    int t = threadIdx.x;
    for (int e = t; e < 11 * DD; e += 256) {
        int w = wq * 11 + e / DD;
        int d = e % DD;
        float acc = 0.f;
#pragma unroll
        for (int h = 0; h < HH; ++h)
            acc += (float)part[((size_t)(bn * HH + h) * WW + w) * DD + d];
        int k = n * WW + w;
        dp_g[(size_t)(b * KPAD + k) * DPAD + d] = (__bf16)acc;
    }
}

// ---------------- K4: feat max over H -> fpT bf16 [b][c][288] ----------------
__global__ __launch_bounds__(256) void k4_featmax(const float* __restrict__ feat,
                                                  __bf16* __restrict__ fpT_g) {
    int tid = blockIdx.x * 256 + threadIdx.x;
    if (tid >= BN * CF * WW) return;
    int bn = tid / (CF * WW);
    int r  = tid % (CF * WW);
    int c = r / WW, w = r % WW;
    float m = -1e30f;
    for (int h = 0; h < HH; ++h)
        m = fmaxf(m, feat[((bn * CF + c) * HH + h) * WW + w]);
    int b = bn / NCAM, n = bn % NCAM;
    fpT_g[(size_t)b * (CF * KPAD) + c * KPAD + n * WW + w] = (__bf16)m;
}

// ---------------- K5: fused MatrixVT projection via MFMA bf16 ----------------
__global__ __launch_bounds__(256, 2) void k5_bev(const __bf16* __restrict__ dp_g,
                                                 const __bf16* __restrict__ fpT_g,
                                                 const float* __restrict__ circle,
                                                 const float* __restrict__ ray,
                                                 float* __restrict__ out) {
    int b  = blockIdx.x >> 8;
    int vt = blockIdx.x & 255;
    int v0 = vt * VT;
    __shared__ __align__(16) __bf16 circleT[VT][136];
    __shared__ __align__(16) __bf16 dps[KC][136];
    __shared__ __align__(16) __bf16 plds[VT][104];
    __shared__ __align__(16) __bf16 fts[CF][104];
    int t = threadIdx.x;
    int wv = t >> 6;
    int lane = t & 63;
    int r16 = lane & 15;
    int kg4 = lane >> 4;

    const float* cb = circle + (size_t)b * DD * XY + v0;
    for (int e = t; e < DD * (VT / 4); e += 256) {
        int d = e >> 4, vq = e & 15;
        float4 cv = *(const float4*)&cb[(size_t)d * XY + vq * 4];
        circleT[vq * 4 + 0][d] = (__bf16)cv.x;
        circleT[vq * 4 + 1][d] = (__bf16)cv.y;
        circleT[vq * 4 + 2][d] = (__bf16)cv.z;
        circleT[vq * 4 + 3][d] = (__bf16)cv.w;
    }
    for (int e = t; e < VT * 16; e += 256) {
        int v = e >> 4, d = DD + (e & 15);
        circleT[v][d] = (__bf16)0.f;
    }

    f32x4 acc[5];
#pragma unroll
    for (int n = 0; n < 5; ++n) acc[n] = (f32x4){0.f, 0.f, 0.f, 0.f};

    const __bf16* dpb = dp_g + (size_t)b * (KPAD * DPAD);
    const __bf16* ftb = fpT_g + (size_t)b * (CF * KPAD);
    const float* rayb = ray + (size_t)b * KTOT * XY + v0;
    int vloc = wv * 16 + kg4 * 4;

    for (int cc = 0; cc < 3; ++cc) {
        int k0 = cc * KC;
        __syncthreads();
        for (int e = t; e < KC * 16; e += 256) {
            int kk = e >> 4, dg = e & 15;
            uint4 u = *(const uint4*)(dpb + (size_t)(k0 + kk) * DPAD + dg * 8);
            *(uint4*)&dps[kk][dg * 8] = u;
        }
        for (int e = t; e < CF * 12; e += 256) {
            int c = e / 12, kg = e % 12;
            uint4 u = *(const uint4*)(ftb + (size_t)c * KPAD + k0 + kg * 8);
            *(uint4*)&fts[c][kg * 8] = u;
        }
        __syncthreads();

        f32x4 pc[6];
#pragma unroll
        for (int n = 0; n < 6; ++n) pc[n] = (f32x4){0.f, 0.f, 0.f, 0.f};
#pragma unroll
        for (int ks = 0; ks < 4; ++ks) {
            bf16x8 af = *(const bf16x8*)&circleT[wv * 16 + r16][ks * 32 + kg4 * 8];
#pragma unroll
            for (int n = 0; n < 6; ++n) {
                bf16x8 bfv = *(const bf16x8*)&dps[n * 16 + r16][ks * 32 + kg4 * 8];
                pc[n] = __builtin_amdgcn_mfma_f32_16x16x32_bf16(af, bfv, pc[n], 0, 0, 0);
            }
        }
#pragma unroll
        for (int n = 0; n < 6; ++n) {
            int k = k0 + n * 16 + r16;
            float4 rv = {0.f, 0.f, 0.f, 0.f};
            if (k < KTOT) rv = *(const float4*)&rayb[(size_t)k * XY + vloc];
            float rvv[4] = {rv.x, rv.y, rv.z, rv.w};
#pragma unroll
            for (int j = 0; j < 4; ++j)
                plds[vloc + j][n * 16 + r16] = (__bf16)(pc[n][j] * rvv[j]);
        }
        __syncthreads();

#pragma unroll
        for (int ks = 0; ks < 3; ++ks) {
            bf16x8 a2 = *(const bf16x8*)&plds[wv * 16 + r16][ks * 32 + kg4 * 8];
#pragma unroll
            for (int n = 0; n < 5; ++n) {
                bf16x8 b2v = *(const bf16x8*)&fts[n * 16 + r16][ks * 32 + kg4 * 8];
                acc[n] = __builtin_amdgcn_mfma_f32_16x16x32_bf16(a2, b2v, acc[n], 0, 0, 0);
            }
        }
    }

    float* ob = out + (size_t)b * CF * XY + v0 + vloc;
#pragma unroll
    for (int n = 0; n < 5; ++n) {
        int c = n * 16 + r16;
        *(float4*)&ob[(size_t)c * XY] = *(float4*)&acc[n];
    }
}

extern "C" void kernel_launch(void* const* d_in, const int* in_sizes, int n_in,
                              void* d_out, int out_size, void* d_ws, size_t ws_size,
                              hipStream_t stream) {
    const float* feat   = (const float*)d_in[0];
    const float* dl     = (const float*)d_in[1];
    const float* circle = (const float*)d_in[2];
    const float* ray    = (const float*)d_in[3];
    const float* w1     = (const float*)d_in[4];
    const float* b1     = (const float*)d_in[5];
    const float* w2     = (const float*)d_in[6];
    const float* b2     = (const float*)d_in[7];
    float* out = (float*)d_out;

    __bf16* dp_g  = (__bf16*)d_ws;                        // 4*288*128
    __bf16* fpT_g = dp_g + BATCH * KPAD * DPAD;           // 4*80*288
    size_t bf16_bytes = (size_t)(BATCH * KPAD * DPAD + BATCH * CF * KPAD) * 2;  // 479232
    float* hbuf = (float*)((char*)d_ws + bf16_bytes);     // 24*16*44*64 f32 NHWC
    float* lg   = hbuf + (size_t)BN * HH * WW * C2;
    float* vw   = lg + BN * HH * WW;
    __bf16* wpk = (__bf16*)(vw + BN * HH * WW);           // 9*64*96
    __bf16* part = wpk + 9 * C2 * CIP;                    // 24*16*44*112 bf16 ~3.8MB

    hipMemsetAsync(d_ws, 0, bf16_bytes, stream);
    hipLaunchKernelGGL(k0_prepack, dim3(216), dim3(256), 0, stream, w1, wpk);
    hipLaunchKernelGGL(k1_conv1, dim3(384), dim3(256), 0, stream, feat, wpk, b1, hbuf);
    hipLaunchKernelGGL(k2a_logits, dim3(384), dim3(256), 0, stream, hbuf, w2, b2, lg);
    hipLaunchKernelGGL(k2b_softmaxh, dim3(24), dim3(64), 0, stream, lg, vw);
    hipLaunchKernelGGL(k3a_depth, dim3(384), dim3(256), 0, stream, dl, vw, part);
    hipLaunchKernelGGL(k3b_hsum, dim3(96), dim3(256), 0, stream, part, dp_g);
    hipLaunchKernelGGL(k4_featmax, dim3((BN * CF * WW + 255) / 256), dim3(256), 0, stream, feat, fpT_g);
    hipLaunchKernelGGL(k5_bev, dim3(BATCH * (XY / VT)), dim3(256), 0, stream, dp_g, fpT_g, circle, ray, out);
}